// Round 18
// baseline (314.419 us; speedup 1.0000x reference)
//
#include <hip/hip_runtime.h>
#include <stdint.h>

#define E_DIM   1024
#define HNUM    16
#define DH      64
#define BATCH   2
#define SEQ     2048
#define M_TOT   (BATCH*SEQ)   // 4096
#define LOG2E   1.44269504088896340736f

typedef __bf16 bf16x8 __attribute__((ext_vector_type(8)));
typedef __bf16 bf16x4 __attribute__((ext_vector_type(4)));
typedef float  f32x4  __attribute__((ext_vector_type(4)));
typedef float  f32x16 __attribute__((ext_vector_type(16)));
typedef unsigned short u16;
typedef unsigned int   u32;
typedef unsigned long long u64;
typedef u16 u16x8 __attribute__((ext_vector_type(8)));
typedef u32 u32x2 __attribute__((ext_vector_type(2)));
typedef u32 u32x4 __attribute__((ext_vector_type(4)));

__device__ __forceinline__ u16 f2bf(float f) {
    u32 u = __builtin_bit_cast(u32, f);
    u32 r = 0x7FFFu + ((u >> 16) & 1u);
    return (u16)((u + r) >> 16);
}

__device__ __forceinline__ void gload_lds16(const u16* g, u16* l) {
    __builtin_amdgcn_global_load_lds(
        (const __attribute__((address_space(1))) u32*)g,
        (__attribute__((address_space(3))) u32*)l, 16, 0, 0);
}

__device__ __forceinline__ u32 cvt_pk_bf16(float lo, float hi) {
    u32 r;
    asm("v_cvt_pk_bf16_f32 %0, %1, %2" : "=v"(r) : "v"(lo), "v"(hi));
    return r;
}

#define MFMA16(a,b,c) __builtin_amdgcn_mfma_f32_16x16x32_bf16((a),(b),(c),0,0,0)
#define MFMA32(a,b,c) __builtin_amdgcn_mfma_f32_32x32x16_bf16((a),(b),(c),0,0,0)

// ---------------- prep: cast x + mask bitmaps + weight transpose + zero tickets ----------------
__global__ __launch_bounds__(256) void prep_kernel(
    const float* __restrict__ x, u16* __restrict__ out,
    const int* __restrict__ mask, u64* __restrict__ bits,
    const float* __restrict__ w0, const float* __restrict__ w1,
    const float* __restrict__ w2, const float* __restrict__ w3,
    u16* __restrict__ wt, u32* __restrict__ flags) {
    __shared__ float tile[32][33];
    const int bid = blockIdx.x;
    const int tid = threadIdx.x;
    if (bid < M_TOT * E_DIM / 1024) {
        const int idx = (bid * 256 + tid) * 4;
        float4 v = *reinterpret_cast<const float4*>(x + idx);
        ushort4 o;
        o.x = f2bf(v.x); o.y = f2bf(v.y); o.z = f2bf(v.z); o.w = f2bf(v.w);
        *reinterpret_cast<ushort4*>(out + idx) = o;
        if (bid < M_TOT / 256) {
            const int i = bid * 256 + tid;
            u64 bl = __ballot(mask[i] != 0);
            if ((i & 63) == 0) bits[i >> 6] = bl;
        }
        if (bid == 0) flags[tid] = 0;   // 256 pair-tickets
    } else {
        const int wb = bid - M_TOT * E_DIM / 1024;
        const int z = wb >> 10;
        const int rem = wb & 1023;
        const int n0 = (rem & 31) * 32, k0 = (rem >> 5) * 32;
        const int tx = tid & 31, ty = tid >> 5;
        const float* w = z == 0 ? w0 : z == 1 ? w1 : z == 2 ? w2 : w3;
        #pragma unroll
        for (int j = 0; j < 4; j++) {
            int k = k0 + ty + j * 8;
            tile[ty + j * 8][tx] = w[(size_t)k * E_DIM + n0 + tx];
        }
        __syncthreads();
        u16* o = wt + (size_t)z * E_DIM * E_DIM;
        #pragma unroll
        for (int j = 0; j < 4; j++) {
            int n = n0 + ty + j * 8;
            o[(size_t)n * E_DIM + k0 + tx] = f2bf(tile[tx][ty + j * 8]);
        }
    }
}

// ---------------- GEMM: C[z] = A @ Wt[z]^T + bias[z], scale on z==0 ----------------
template <typename OutT>
__global__ __launch_bounds__(256) void gemm_kernel(
    const u16* __restrict__ A, const u16* __restrict__ Bt_base, OutT* __restrict__ C_base,
    const float* __restrict__ bias0, const float* __restrict__ bias1,
    const float* __restrict__ bias2, float scale0, int Mdim) {
    const int z = blockIdx.z;
    const u16* Bt = Bt_base + (size_t)z * E_DIM * E_DIM;
    OutT* C = C_base + (size_t)z * Mdim * E_DIM;
    const float* bias = (z == 0) ? bias0 : (z == 1 ? bias1 : bias2);
    const float scale = (z == 0) ? scale0 : 1.0f;

    __shared__ __align__(16) u16 Als[128 * 32];
    __shared__ __align__(16) u16 Bls[128 * 32];

    const int tid = threadIdx.x;
    const int lane = tid & 63;
    const int w = tid >> 6;
    const int wr = (w >> 1) * 64, wc = (w & 1) * 64;
    const int tm = blockIdx.y * 128, tn = blockIdx.x * 128;
    const int r4 = tid >> 2;
    const int c8 = (tid & 3) * 8;

    f32x4 acc[4][4] = {};

    for (int k0 = 0; k0 < E_DIM; k0 += 32) {
        gload_lds16(A + (size_t)(tm + r4) * E_DIM + k0 + c8, Als + tid * 8);
        gload_lds16(A + (size_t)(tm + 64 + r4) * E_DIM + k0 + c8, Als + 2048 + tid * 8);
        gload_lds16(Bt + (size_t)(tn + r4) * E_DIM + k0 + c8, Bls + tid * 8);
        gload_lds16(Bt + (size_t)(tn + 64 + r4) * E_DIM + k0 + c8, Bls + 2048 + tid * 8);
        __syncthreads();
        const int lr = lane & 15, lg = lane >> 4;
        bf16x8 af[4], bfr[4];
        #pragma unroll
        for (int m = 0; m < 4; m++)
            af[m] = *reinterpret_cast<const bf16x8*>(Als + (wr + m * 16 + lr) * 32 + lg * 8);
        #pragma unroll
        for (int n = 0; n < 4; n++)
            bfr[n] = *reinterpret_cast<const bf16x8*>(Bls + (wc + n * 16 + lr) * 32 + lg * 8);
        #pragma unroll
        for (int m = 0; m < 4; m++)
            #pragma unroll
            for (int n = 0; n < 4; n++)
                acc[m][n] = MFMA16(af[m], bfr[n], acc[m][n]);
        __syncthreads();
    }

    const int lr = lane & 15, lg = lane >> 4;
    #pragma unroll
    for (int m = 0; m < 4; m++) {
        #pragma unroll
        for (int n = 0; n < 4; n++) {
            const int col = tn + wc + n * 16 + lr;
            const float bv = bias[col];
            #pragma unroll
            for (int r = 0; r < 4; r++) {
                const int row = tm + wr + m * 16 + lg * 4 + r;
                float v = (acc[m][n][r] + bv) * scale;
                if constexpr (sizeof(OutT) == 2) {
                    C[(size_t)row * E_DIM + col] = f2bf(v);
                } else {
                    C[(size_t)row * E_DIM + col] = v;
                }
            }
        }
    }
}

// ---------------- flash attention + fused combine (last block of each half-pair) ----------
// R17 loop byte-identical. Epilogue: store PO+lws -> threadfence -> ticket atomic;
// second finisher of each (h,b,qt) pair re-reads both halves, normalizes, writes ab.
__global__ __launch_bounds__(512) void attn_kernel(
    const u16* __restrict__ Q, const u16* __restrict__ K, const u16* __restrict__ V,
    const u64* __restrict__ mbits, u16* __restrict__ PO, float* __restrict__ lws,
    u32* __restrict__ flags, u16* __restrict__ ab) {
    __shared__ __align__(16) u16 Kls[4][64 * 64];   // 32KB ring, slot stride 8192B
    __shared__ __align__(16) u16 Vt[2][64 * 64];    // 16KB dbuf, slot stride 8192B
    __shared__ int ticket_old;

    const int tid = threadIdx.x;          // 0..511
    const int lane = tid & 63;
    const int wave = tid >> 6;            // 0..7
    const int sub = wave >> 2;
    const int wg = wave & 3;
    const int hi = lane >> 5;
    const int l31 = lane & 31;
    const int n = blockIdx.x;
    const int g = n & 63, qt = n >> 6;
    const int h = g & 15, zz = g >> 4;
    const int b = zz >> 1, half = zz & 1;

    const int qrow = b * SEQ + qt * 256 + sub * 128 + wg * 32 + l31;
    bf16x8 qf[4];
    #pragma unroll
    for (int kc = 0; kc < 4; kc++)
        qf[kc] = *reinterpret_cast<const bf16x8*>(Q + (size_t)qrow * E_DIM + h * DH + kc * 16 + hi * 8);

    const int krow = (l31 & 3) | ((l31 & 4) << 1) | ((l31 & 8) >> 1) | (l31 & 16);
    const u32 ksw = (u32)(krow & 7) << 4;
    u32 koff[4];
    #pragma unroll
    for (int kc = 0; kc < 4; kc++)
        koff[kc] = (((u32)krow * 128) + (u32)kc * 32 + (u32)hi * 16) ^ ksw;

    const int krA = tid >> 3;
    const int kcA = (tid & 7) ^ (krA & 7);
    const size_t kgoff = (size_t)krA * E_DIM + kcA * 8;

    const int t8 = tid & 255;
    const int vhalf = tid >> 8;
    const int vc = t8 & 7;
    const int vsg = ((t8 >> 3) ^ (vc << 2)) & 31;
    const size_t vgoff = (size_t)(2 * vsg) * E_DIM + vc * 8 + vhalf * 4;
    u32 vwoff[4];
    #pragma unroll
    for (int jj = 0; jj < 4; jj++) {
        const int j = vhalf * 4 + jj;
        vwoff[jj] = (((u32)(vc * 8 + j) * 128) + (u32)vsg * 4) ^ ((u32)j << 4);
    }
    u32 vroff[4];
    #pragma unroll
    for (int kc = 0; kc < 4; kc++)
        vroff[kc] = (((u32)l31 * 128) + (u32)(2 * kc + hi) * 16) ^ (((u32)(l31 & 7)) << 4);

    f32x16 oacc0 = {}, oacc1 = {};
    f32x4 l4 = {};

    const u16* Kg = K + (size_t)(b * SEQ + half * (SEQ / 2)) * E_DIM + h * DH;
    const u16* Vg = V + (size_t)(b * SEQ + half * (SEQ / 2)) * E_DIM + h * DH;
    const size_t TSTEP = (size_t)64 * E_DIM;
    const u16* kgp = Kg + kgoff;
    const u16* vgp = Vg + vgoff;
    const int NT = SEQ / 2 / 64;   // 16

    {
        u32x2 a0 = *reinterpret_cast<const u32x2*>(vgp);
        u32x2 a1 = *reinterpret_cast<const u32x2*>(vgp + E_DIM);
        gload_lds16(kgp,             &Kls[0][tid * 8]);
        gload_lds16(kgp + TSTEP,     &Kls[1][tid * 8]);
        gload_lds16(kgp + 2 * TSTEP, &Kls[2][tid * 8]);
        kgp += 3 * TSTEP; vgp += TSTEP;
        asm volatile("s_waitcnt vmcnt(1)" ::: "memory");
        __builtin_amdgcn_sched_barrier(0);
        #pragma unroll
        for (int jj = 0; jj < 4; jj++)
            *(u32*)((char*)Vt + vwoff[jj]) = __builtin_amdgcn_perm(
                a1[jj >> 1], a0[jj >> 1], (jj & 1) ? 0x07060302u : 0x05040100u);
        asm volatile("s_waitcnt lgkmcnt(0)" ::: "memory");
        __builtin_amdgcn_sched_barrier(0);
        __builtin_amdgcn_s_barrier();
    }

    f32x16 sc0 = {}, sc1 = {}, sn0, sn1;
    {
        const char* Kb = (const char*)Kls;
        __builtin_amdgcn_s_setprio(1);
        #pragma unroll
        for (int kc = 0; kc < 4; kc++) {
            bf16x8 kf0 = *(const bf16x8*)(Kb + koff[kc]);
            bf16x8 kf1 = *(const bf16x8*)(Kb + koff[kc] + 4096);
            sc0 = MFMA32(kf0, qf[kc], sc0);
            sc1 = MFMA32(kf1, qf[kc], sc1);
        }
        __builtin_amdgcn_s_setprio(0);
    }

#define ATTN_TILE(T, CUR0, CUR1, NXT0, NXT1)                                           \
    {                                                                                  \
        const int t_ = (T);                                                            \
        const bool haveV = (t_ + 1 < NT);                                              \
        const bool haveK = (t_ + 3 < NT);                                              \
        u32x2 a0, a1;                                                                  \
        if (haveV) {                                                                   \
            a0 = *reinterpret_cast<const u32x2*>(vgp);                                 \
            a1 = *reinterpret_cast<const u32x2*>(vgp + E_DIM);                         \
        }                                                                              \
        if (haveK) gload_lds16(kgp, &Kls[(t_ + 3) & 3][tid * 8]);                      \
        const u64 mb = mbits[b * (SEQ / 64) + half * NT + t_];                         \
        if (mb != ~0ull) {                                                             \
            _Pragma("unroll")                                                          \
            for (int r = 0; r < 16; r++) {                                             \
                const int key = (r & 3) + 4 * ((r >> 2) & 1) + 8 * hi + 16 * ((r >> 3) & 1); \
                if (!((mb >> key) & 1))        CUR0[r] += -1.442695e9f;                \
                if (!((mb >> (32 + key)) & 1)) CUR1[r] += -1.442695e9f;                \
            }                                                                          \
        }                                                                              \
        _Pragma("unroll")                                                              \
        for (int r = 0; r < 16; r++) {                                                 \
            CUR0[r] = __builtin_amdgcn_exp2f(CUR0[r]); l4[r & 3] += CUR0[r];           \
        }                                                                              \
        _Pragma("unroll")                                                              \
        for (int r = 0; r < 16; r++) {                                                 \
            CUR1[r] = __builtin_amdgcn_exp2f(CUR1[r]); l4[r & 3] += CUR1[r];           \
        }                                                                              \
        bf16x8 pf[4];                                                                  \
        {                                                                              \
            u32x4 pw0, pw1, pw2, pw3;                                                  \
            _Pragma("unroll")                                                          \
            for (int e = 0; e < 4; e++) {                                              \
                pw0[e] = cvt_pk_bf16(CUR0[2 * e],     CUR0[2 * e + 1]);                \
                pw1[e] = cvt_pk_bf16(CUR0[8 + 2 * e], CUR0[9 + 2 * e]);                \
                pw2[e] = cvt_pk_bf16(CUR1[2 * e],     CUR1[2 * e + 1]);                \
                pw3[e] = cvt_pk_bf16(CUR1[8 + 2 * e], CUR1[9 + 2 * e]);                \
            }                                                                          \
            pf[0] = __builtin_bit_cast(bf16x8, pw0);                                   \
            pf[1] = __builtin_bit_cast(bf16x8, pw1);                                   \
            pf[2] = __builtin_bit_cast(bf16x8, pw2);                                   \
            pf[3] = __builtin_bit_cast(bf16x8, pw3);                                   \
        }                                                                              \
        NXT0 = f32x16{};                                                               \
        NXT1 = f32x16{};                                                               \
        if (haveV) {                                                                   \
            const char* Kb = (const char*)Kls + ((t_ + 1) & 3) * 8192;                 \
            __builtin_amdgcn_s_setprio(1);                                             \
            _Pragma("unroll")                                                          \
            for (int kc = 0; kc < 4; kc++) {                                           \
                bf16x8 kf0 = *(const bf16x8*)(Kb + koff[kc]);                          \
                bf16x8 kf1 = *(const bf16x8*)(Kb + koff[kc] + 4096);                   \
                NXT0 = MFMA32(kf0, qf[kc], NXT0);                                      \
                NXT1 = MFMA32(kf1, qf[kc], NXT1);                                      \
            }                                                                          \
            __builtin_amdgcn_s_setprio(0);                                             \
        }                                                                              \
        {                                                                              \
            const char* Vb = (const char*)Vt + (t_ & 1) * 8192;                        \
            __builtin_amdgcn_s_setprio(1);                                             \
            _Pragma("unroll")                                                          \
            for (int kc = 0; kc < 4; kc++) {                                           \
                bf16x8 vf0 = *(const bf16x8*)(Vb + vroff[kc]);                         \
                bf16x8 vf1 = *(const bf16x8*)(Vb + vroff[kc] + 4096);                  \
                oacc0 = MFMA32(vf0, pf[kc], oacc0);                                    \
                oacc1 = MFMA32(vf1, pf[kc], oacc1);                                    \
            }                                                                          \
            __builtin_amdgcn_s_setprio(0);                                             \
        }                                                                              \
        asm volatile("s_waitcnt vmcnt(1)" ::: "memory");                               \
        __builtin_amdgcn_sched_barrier(0);                                             \
        if (haveV) {                                                                   \
            _Pragma("unroll")                                                          \
            for (int jj = 0; jj < 4; jj++)                                             \
                *(u32*)((char*)Vt + ((t_ + 1) & 1) * 8192 + vwoff[jj]) =               \
                    __builtin_amdgcn_perm(a1[jj >> 1], a0[jj >> 1],                    \
                                          (jj & 1) ? 0x07060302u : 0x05040100u);       \
        }                                                                              \
        asm volatile("s_waitcnt lgkmcnt(0)" ::: "memory");                             \
        __builtin_amdgcn_sched_barrier(0);                                             \
        __builtin_amdgcn_s_barrier();                                                  \
        if (haveK) kgp += TSTEP;                                                       \
        if (haveV) vgp += TSTEP;                                                       \
    }

    for (int tp = 0; tp < NT / 2; tp++) {
        ATTN_TILE(2 * tp,     sc0, sc1, sn0, sn1)
        ATTN_TILE(2 * tp + 1, sn0, sn1, sc0, sc1)
    }
#undef ATTN_TILE

    // ---- store UNNORMALIZED partials + l ----
    const float l_run = (l4[0] + l4[1]) + (l4[2] + l4[3]);
    const float l_tot = l_run + __shfl_xor(l_run, 32);
    u16* op = PO + ((size_t)half * M_TOT + qrow) * E_DIM + h * DH;
    #pragma unroll
    for (int db = 0; db < 2; db++) {
        #pragma unroll
        for (int j = 0; j < 4; j++) {
            u32x2 pk;
            pk[0] = cvt_pk_bf16(db ? oacc1[4 * j + 0] : oacc0[4 * j + 0],
                                db ? oacc1[4 * j + 1] : oacc0[4 * j + 1]);
            pk[1] = cvt_pk_bf16(db ? oacc1[4 * j + 2] : oacc0[4 * j + 2],
                                db ? oacc1[4 * j + 3] : oacc0[4 * j + 3]);
            const int d0 = 32 * db + 8 * j + 4 * hi;
            *reinterpret_cast<u32x2*>(op + d0) = pk;
        }
    }
    if (hi == 0) lws[((size_t)half * M_TOT + qrow) * HNUM + h] = l_tot;

    // ---- fused combine: second finisher of the (h,b,qt) pair merges both halves ----
    __threadfence();            // release this block's PO/lws stores (device scope)
    __syncthreads();            // all threads' stores+fences precede the ticket
    if (tid == 0) ticket_old = (int)atomicAdd(&flags[h + 16 * b + 32 * qt], 1u);
    __syncthreads();
    if (ticket_old == 1) {
        __threadfence();        // acquire: peer's stores visible after its ticket
        const int rbase = b * SEQ + qt * 256;
        #pragma unroll
        for (int i = 0; i < 4; i++) {
            const int c = tid + 512 * i;            // 0..2047
            const int row = rbase + (c >> 3);
            const int col = h * DH + (c & 7) * 8;
            const float l0 = lws[(size_t)row * HNUM + h];
            const float l1 = lws[((size_t)M_TOT + row) * HNUM + h];
            const float rl = 1.0f / (l0 + l1);
            const bf16x8 pa = *reinterpret_cast<const bf16x8*>(
                PO + (size_t)row * E_DIM + col);
            const bf16x8 pb = *reinterpret_cast<const bf16x8*>(
                PO + ((size_t)M_TOT + row) * E_DIM + col);
            u16x8 o;
            #pragma unroll
            for (int j = 0; j < 8; j++)
                o[j] = f2bf(((float)pa[j] + (float)pb[j]) * rl);
            *reinterpret_cast<u16x8*>(ab + (size_t)row * E_DIM + col) = o;
        }
    }
}

extern "C" void kernel_launch(void* const* d_in, const int* in_sizes, int n_in,
                              void* d_out, int out_size, void* d_ws, size_t ws_size,
                              hipStream_t stream) {
    const float* x  = (const float*)d_in[0];
    const int* mask = (const int*)d_in[1];
    const float* Wq = (const float*)d_in[2];
    const float* bq = (const float*)d_in[3];
    const float* Wk = (const float*)d_in[4];
    const float* bk = (const float*)d_in[5];
    const float* Wv = (const float*)d_in[6];
    const float* bv = (const float*)d_in[7];
    const float* Wo = (const float*)d_in[8];
    const float* bo = (const float*)d_in[9];
    float* out = (float*)d_out;

    u16* ws  = (u16*)d_ws;
    const size_t ME = (size_t)M_TOT * E_DIM;         // 4194304
    u16* xb  = ws;                                   // [M][E] bf16 x ; later reused as ab
    u16* wt  = ws + ME;                              // 4x [E][E] bf16 W^T (q,k,v,o)
    u16* qb  = ws + 2 * ME;                          // Q,K,V contiguous [3][M][E]
    u16* kbf = ws + 3 * ME;
    u16* vbf = ws + 4 * ME;
    u64* mbf = (u64*)(ws + 5 * ME);                  // 64 u64 mask bitmaps (512B)
    float* lws = (float*)(ws + 5 * ME + 8192);       // [2][M][H] f32 l-partials (512KB)
    u32* flags = (u32*)(ws + 5 * ME + 8192 + 262144); // 256 pair-tickets (1KB)
    u16* ab  = xb;                                   // attn concat aliases xb
    u16* po  = (u16*)d_out;                          // partial O scratch: 2x[M][E] bf16 = 16MB

    prep_kernel<<<dim3(M_TOT * E_DIM / 1024 + 4096), dim3(256), 0, stream>>>(
        x, xb, mask, mbf, Wq, Wk, Wv, Wo, wt, flags);
    gemm_kernel<u16><<<dim3(E_DIM / 128, M_TOT / 128, 3), dim3(256), 0, stream>>>(
        xb, wt, qb, bq, bk, bv, 0.125f * LOG2E, M_TOT);
    attn_kernel<<<dim3(512), dim3(512), 0, stream>>>(qb, kbf, vbf, mbf, po, lws, flags, ab);
    gemm_kernel<float><<<dim3(E_DIM / 128, M_TOT / 128, 1), dim3(256), 0, stream>>>(
        ab, wt + (size_t)3 * E_DIM * E_DIM, out, bo, bo, bo, 1.0f, M_TOT);
}

// Round 19
// 122.917 us; speedup vs baseline: 2.5580x; 2.5580x over previous
//
#include <hip/hip_runtime.h>
#include <stdint.h>

#define E_DIM   1024
#define HNUM    16
#define DH      64
#define BATCH   2
#define SEQ     2048
#define M_TOT   (BATCH*SEQ)   // 4096
#define LOG2E   1.44269504088896340736f

typedef __bf16 bf16x8 __attribute__((ext_vector_type(8)));
typedef __bf16 bf16x4 __attribute__((ext_vector_type(4)));
typedef float  f32x4  __attribute__((ext_vector_type(4)));
typedef float  f32x16 __attribute__((ext_vector_type(16)));
typedef unsigned short u16;
typedef unsigned int   u32;
typedef unsigned long long u64;
typedef u16 u16x8 __attribute__((ext_vector_type(8)));
typedef u32 u32x2 __attribute__((ext_vector_type(2)));
typedef u32 u32x4 __attribute__((ext_vector_type(4)));

__device__ __forceinline__ u16 f2bf(float f) {
    u32 u = __builtin_bit_cast(u32, f);
    u32 r = 0x7FFFu + ((u >> 16) & 1u);
    return (u16)((u + r) >> 16);
}

__device__ __forceinline__ void gload_lds16(const u16* g, u16* l) {
    __builtin_amdgcn_global_load_lds(
        (const __attribute__((address_space(1))) u32*)g,
        (__attribute__((address_space(3))) u32*)l, 16, 0, 0);
}

__device__ __forceinline__ u32 cvt_pk_bf16(float lo, float hi) {
    u32 r;
    asm("v_cvt_pk_bf16_f32 %0, %1, %2" : "=v"(r) : "v"(lo), "v"(hi));
    return r;
}

#define MFMA16(a,b,c) __builtin_amdgcn_mfma_f32_16x16x32_bf16((a),(b),(c),0,0,0)
#define MFMA32(a,b,c) __builtin_amdgcn_mfma_f32_32x32x16_bf16((a),(b),(c),0,0,0)

// ---------------- prep: cast x + mask bitmaps + weight transpose (one launch) ----------------
__global__ __launch_bounds__(256) void prep_kernel(
    const float* __restrict__ x, u16* __restrict__ out,
    const int* __restrict__ mask, u64* __restrict__ bits,
    const float* __restrict__ w0, const float* __restrict__ w1,
    const float* __restrict__ w2, const float* __restrict__ w3,
    u16* __restrict__ wt) {
    __shared__ float tile[32][33];
    const int bid = blockIdx.x;
    const int tid = threadIdx.x;
    if (bid < M_TOT * E_DIM / 1024) {
        const int idx = (bid * 256 + tid) * 4;
        float4 v = *reinterpret_cast<const float4*>(x + idx);
        ushort4 o;
        o.x = f2bf(v.x); o.y = f2bf(v.y); o.z = f2bf(v.z); o.w = f2bf(v.w);
        *reinterpret_cast<ushort4*>(out + idx) = o;
        if (bid < M_TOT / 256) {
            const int i = bid * 256 + tid;
            u64 bl = __ballot(mask[i] != 0);
            if ((i & 63) == 0) bits[i >> 6] = bl;
        }
    } else {
        const int wb = bid - M_TOT * E_DIM / 1024;
        const int z = wb >> 10;
        const int rem = wb & 1023;
        const int n0 = (rem & 31) * 32, k0 = (rem >> 5) * 32;
        const int tx = tid & 31, ty = tid >> 5;
        const float* w = z == 0 ? w0 : z == 1 ? w1 : z == 2 ? w2 : w3;
        #pragma unroll
        for (int j = 0; j < 4; j++) {
            int k = k0 + ty + j * 8;
            tile[ty + j * 8][tx] = w[(size_t)k * E_DIM + n0 + tx];
        }
        __syncthreads();
        u16* o = wt + (size_t)z * E_DIM * E_DIM;
        #pragma unroll
        for (int j = 0; j < 4; j++) {
            int n = n0 + ty + j * 8;
            o[(size_t)n * E_DIM + k0 + tx] = f2bf(tile[tx][ty + j * 8]);
        }
    }
}

// ---------------- GEMM: C[z] = A @ Wt[z]^T + bias[z], scale on z==0 ----------------
template <typename OutT>
__global__ __launch_bounds__(256) void gemm_kernel(
    const u16* __restrict__ A, const u16* __restrict__ Bt_base, OutT* __restrict__ C_base,
    const float* __restrict__ bias0, const float* __restrict__ bias1,
    const float* __restrict__ bias2, float scale0, int Mdim) {
    const int z = blockIdx.z;
    const u16* Bt = Bt_base + (size_t)z * E_DIM * E_DIM;
    OutT* C = C_base + (size_t)z * Mdim * E_DIM;
    const float* bias = (z == 0) ? bias0 : (z == 1 ? bias1 : bias2);
    const float scale = (z == 0) ? scale0 : 1.0f;

    __shared__ __align__(16) u16 Als[128 * 32];
    __shared__ __align__(16) u16 Bls[128 * 32];

    const int tid = threadIdx.x;
    const int lane = tid & 63;
    const int w = tid >> 6;
    const int wr = (w >> 1) * 64, wc = (w & 1) * 64;
    const int tm = blockIdx.y * 128, tn = blockIdx.x * 128;
    const int r4 = tid >> 2;
    const int c8 = (tid & 3) * 8;

    f32x4 acc[4][4] = {};

    for (int k0 = 0; k0 < E_DIM; k0 += 32) {
        gload_lds16(A + (size_t)(tm + r4) * E_DIM + k0 + c8, Als + tid * 8);
        gload_lds16(A + (size_t)(tm + 64 + r4) * E_DIM + k0 + c8, Als + 2048 + tid * 8);
        gload_lds16(Bt + (size_t)(tn + r4) * E_DIM + k0 + c8, Bls + tid * 8);
        gload_lds16(Bt + (size_t)(tn + 64 + r4) * E_DIM + k0 + c8, Bls + 2048 + tid * 8);
        __syncthreads();
        const int lr = lane & 15, lg = lane >> 4;
        bf16x8 af[4], bfr[4];
        #pragma unroll
        for (int m = 0; m < 4; m++)
            af[m] = *reinterpret_cast<const bf16x8*>(Als + (wr + m * 16 + lr) * 32 + lg * 8);
        #pragma unroll
        for (int n = 0; n < 4; n++)
            bfr[n] = *reinterpret_cast<const bf16x8*>(Bls + (wc + n * 16 + lr) * 32 + lg * 8);
        #pragma unroll
        for (int m = 0; m < 4; m++)
            #pragma unroll
            for (int n = 0; n < 4; n++)
                acc[m][n] = MFMA16(af[m], bfr[n], acc[m][n]);
        __syncthreads();
    }

    const int lr = lane & 15, lg = lane >> 4;
    #pragma unroll
    for (int m = 0; m < 4; m++) {
        #pragma unroll
        for (int n = 0; n < 4; n++) {
            const int col = tn + wc + n * 16 + lr;
            const float bv = bias[col];
            #pragma unroll
            for (int r = 0; r < 4; r++) {
                const int row = tm + wr + m * 16 + lg * 4 + r;
                float v = (acc[m][n][r] + bv) * scale;
                if constexpr (sizeof(OutT) == 2) {
                    C[(size_t)row * E_DIM + col] = f2bf(v);
                } else {
                    C[(size_t)row * E_DIM + col] = v;
                }
            }
        }
    }
}

// ---------------- flash attention: R13 structure + ping-pong unroll + l4 partial sums ----
__global__ __launch_bounds__(512) void attn_kernel(
    const u16* __restrict__ Q, const u16* __restrict__ K, const u16* __restrict__ V,
    const u64* __restrict__ mbits, u16* __restrict__ PO, float* __restrict__ lws) {
    __shared__ __align__(16) u16 Kls[4][64 * 64];   // 32KB ring, slot stride 8192B
    __shared__ __align__(16) u16 Vt[2][64 * 64];    // 16KB dbuf, slot stride 8192B

    const int tid = threadIdx.x;          // 0..511
    const int lane = tid & 63;
    const int wave = tid >> 6;            // 0..7
    const int sub = wave >> 2;
    const int wg = wave & 3;
    const int hi = lane >> 5;
    const int l31 = lane & 31;
    const int n = blockIdx.x;
    const int g = n & 63, qt = n >> 6;
    const int h = g & 15, zz = g >> 4;
    const int b = zz >> 1, half = zz & 1;

    const int qrow = b * SEQ + qt * 256 + sub * 128 + wg * 32 + l31;
    bf16x8 qf[4];
    #pragma unroll
    for (int kc = 0; kc < 4; kc++)
        qf[kc] = *reinterpret_cast<const bf16x8*>(Q + (size_t)qrow * E_DIM + h * DH + kc * 16 + hi * 8);

    const int krow = (l31 & 3) | ((l31 & 4) << 1) | ((l31 & 8) >> 1) | (l31 & 16);
    const u32 ksw = (u32)(krow & 7) << 4;
    u32 koff[4];
    #pragma unroll
    for (int kc = 0; kc < 4; kc++)
        koff[kc] = (((u32)krow * 128) + (u32)kc * 32 + (u32)hi * 16) ^ ksw;

    const int krA = tid >> 3;
    const int kcA = (tid & 7) ^ (krA & 7);
    const size_t kgoff = (size_t)krA * E_DIM + kcA * 8;

    const int t8 = tid & 255;
    const int vhalf = tid >> 8;
    const int vc = t8 & 7;
    const int vsg = ((t8 >> 3) ^ (vc << 2)) & 31;
    const size_t vgoff = (size_t)(2 * vsg) * E_DIM + vc * 8 + vhalf * 4;
    u32 vwoff[4];
    #pragma unroll
    for (int jj = 0; jj < 4; jj++) {
        const int j = vhalf * 4 + jj;
        vwoff[jj] = (((u32)(vc * 8 + j) * 128) + (u32)vsg * 4) ^ ((u32)j << 4);
    }
    u32 vroff[4];
    #pragma unroll
    for (int kc = 0; kc < 4; kc++)
        vroff[kc] = (((u32)l31 * 128) + (u32)(2 * kc + hi) * 16) ^ (((u32)(l31 & 7)) << 4);

    f32x16 oacc0 = {}, oacc1 = {};
    f32x4 l4 = {};

    const u16* Kg = K + (size_t)(b * SEQ + half * (SEQ / 2)) * E_DIM + h * DH;
    const u16* Vg = V + (size_t)(b * SEQ + half * (SEQ / 2)) * E_DIM + h * DH;
    const size_t TSTEP = (size_t)64 * E_DIM;
    const u16* kgp = Kg + kgoff;
    const u16* vgp = Vg + vgoff;
    const int NT = SEQ / 2 / 64;   // 16

    {
        u32x2 a0 = *reinterpret_cast<const u32x2*>(vgp);
        u32x2 a1 = *reinterpret_cast<const u32x2*>(vgp + E_DIM);
        gload_lds16(kgp,             &Kls[0][tid * 8]);
        gload_lds16(kgp + TSTEP,     &Kls[1][tid * 8]);
        gload_lds16(kgp + 2 * TSTEP, &Kls[2][tid * 8]);
        kgp += 3 * TSTEP; vgp += TSTEP;
        asm volatile("s_waitcnt vmcnt(1)" ::: "memory");
        __builtin_amdgcn_sched_barrier(0);
        #pragma unroll
        for (int jj = 0; jj < 4; jj++)
            *(u32*)((char*)Vt + vwoff[jj]) = __builtin_amdgcn_perm(
                a1[jj >> 1], a0[jj >> 1], (jj & 1) ? 0x07060302u : 0x05040100u);
        asm volatile("s_waitcnt lgkmcnt(0)" ::: "memory");
        __builtin_amdgcn_sched_barrier(0);
        __builtin_amdgcn_s_barrier();
    }

    f32x16 sc0 = {}, sc1 = {}, sn0, sn1;
    {
        const char* Kb = (const char*)Kls;
        __builtin_amdgcn_s_setprio(1);
        #pragma unroll
        for (int kc = 0; kc < 4; kc++) {
            bf16x8 kf0 = *(const bf16x8*)(Kb + koff[kc]);
            bf16x8 kf1 = *(const bf16x8*)(Kb + koff[kc] + 4096);
            sc0 = MFMA32(kf0, qf[kc], sc0);
            sc1 = MFMA32(kf1, qf[kc], sc1);
        }
        __builtin_amdgcn_s_setprio(0);
    }

#define ATTN_TILE(T, CUR0, CUR1, NXT0, NXT1)                                           \
    {                                                                                  \
        const int t_ = (T);                                                            \
        const bool haveV = (t_ + 1 < NT);                                              \
        const bool haveK = (t_ + 3 < NT);                                              \
        u32x2 a0, a1;                                                                  \
        if (haveV) {                                                                   \
            a0 = *reinterpret_cast<const u32x2*>(vgp);                                 \
            a1 = *reinterpret_cast<const u32x2*>(vgp + E_DIM);                         \
        }                                                                              \
        if (haveK) gload_lds16(kgp, &Kls[(t_ + 3) & 3][tid * 8]);                      \
        const u64 mb = mbits[b * (SEQ / 64) + half * NT + t_];                         \
        if (mb != ~0ull) {                                                             \
            _Pragma("unroll")                                                          \
            for (int r = 0; r < 16; r++) {                                             \
                const int key = (r & 3) + 4 * ((r >> 2) & 1) + 8 * hi + 16 * ((r >> 3) & 1); \
                if (!((mb >> key) & 1))        CUR0[r] += -1.442695e9f;                \
                if (!((mb >> (32 + key)) & 1)) CUR1[r] += -1.442695e9f;                \
            }                                                                          \
        }                                                                              \
        _Pragma("unroll")                                                              \
        for (int r = 0; r < 16; r++) {                                                 \
            CUR0[r] = __builtin_amdgcn_exp2f(CUR0[r]); l4[r & 3] += CUR0[r];           \
        }                                                                              \
        _Pragma("unroll")                                                              \
        for (int r = 0; r < 16; r++) {                                                 \
            CUR1[r] = __builtin_amdgcn_exp2f(CUR1[r]); l4[r & 3] += CUR1[r];           \
        }                                                                              \
        bf16x8 pf[4];                                                                  \
        {                                                                              \
            u32x4 pw0, pw1, pw2, pw3;                                                  \
            _Pragma("unroll")                                                          \
            for (int e = 0; e < 4; e++) {                                              \
                pw0[e] = cvt_pk_bf16(CUR0[2 * e],     CUR0[2 * e + 1]);                \
                pw1[e] = cvt_pk_bf16(CUR0[8 + 2 * e], CUR0[9 + 2 * e]);                \
                pw2[e] = cvt_pk_bf16(CUR1[2 * e],     CUR1[2 * e + 1]);                \
                pw3[e] = cvt_pk_bf16(CUR1[8 + 2 * e], CUR1[9 + 2 * e]);                \
            }                                                                          \
            pf[0] = __builtin_bit_cast(bf16x8, pw0);                                   \
            pf[1] = __builtin_bit_cast(bf16x8, pw1);                                   \
            pf[2] = __builtin_bit_cast(bf16x8, pw2);                                   \
            pf[3] = __builtin_bit_cast(bf16x8, pw3);                                   \
        }                                                                              \
        NXT0 = f32x16{};                                                               \
        NXT1 = f32x16{};                                                               \
        if (haveV) {                                                                   \
            const char* Kb = (const char*)Kls + ((t_ + 1) & 3) * 8192;                 \
            __builtin_amdgcn_s_setprio(1);                                             \
            _Pragma("unroll")                                                          \
            for (int kc = 0; kc < 4; kc++) {                                           \
                bf16x8 kf0 = *(const bf16x8*)(Kb + koff[kc]);                          \
                bf16x8 kf1 = *(const bf16x8*)(Kb + koff[kc] + 4096);                   \
                NXT0 = MFMA32(kf0, qf[kc], NXT0);                                      \
                NXT1 = MFMA32(kf1, qf[kc], NXT1);                                      \
            }                                                                          \
            __builtin_amdgcn_s_setprio(0);                                             \
        }                                                                              \
        {                                                                              \
            const char* Vb = (const char*)Vt + (t_ & 1) * 8192;                        \
            __builtin_amdgcn_s_setprio(1);                                             \
            _Pragma("unroll")                                                          \
            for (int kc = 0; kc < 4; kc++) {                                           \
                bf16x8 vf0 = *(const bf16x8*)(Vb + vroff[kc]);                         \
                bf16x8 vf1 = *(const bf16x8*)(Vb + vroff[kc] + 4096);                  \
                oacc0 = MFMA32(vf0, pf[kc], oacc0);                                    \
                oacc1 = MFMA32(vf1, pf[kc], oacc1);                                    \
            }                                                                          \
            __builtin_amdgcn_s_setprio(0);                                             \
        }                                                                              \
        asm volatile("s_waitcnt vmcnt(1)" ::: "memory");                               \
        __builtin_amdgcn_sched_barrier(0);                                             \
        if (haveV) {                                                                   \
            _Pragma("unroll")                                                          \
            for (int jj = 0; jj < 4; jj++)                                             \
                *(u32*)((char*)Vt + ((t_ + 1) & 1) * 8192 + vwoff[jj]) =               \
                    __builtin_amdgcn_perm(a1[jj >> 1], a0[jj >> 1],                    \
                                          (jj & 1) ? 0x07060302u : 0x05040100u);       \
        }                                                                              \
        asm volatile("s_waitcnt lgkmcnt(0)" ::: "memory");                             \
        __builtin_amdgcn_sched_barrier(0);                                             \
        __builtin_amdgcn_s_barrier();                                                  \
        if (haveK) kgp += TSTEP;                                                       \
        if (haveV) vgp += TSTEP;                                                       \
    }

    for (int tp = 0; tp < NT / 2; tp++) {
        ATTN_TILE(2 * tp,     sc0, sc1, sn0, sn1)
        ATTN_TILE(2 * tp + 1, sn0, sn1, sc0, sc1)
    }
#undef ATTN_TILE

    const float l_run = (l4[0] + l4[1]) + (l4[2] + l4[3]);
    const float l_tot = l_run + __shfl_xor(l_run, 32);
    u16* op = PO + ((size_t)half * M_TOT + qrow) * E_DIM + h * DH;
    #pragma unroll
    for (int db = 0; db < 2; db++) {
        #pragma unroll
        for (int j = 0; j < 4; j++) {
            u32x2 pk;
            pk[0] = cvt_pk_bf16(db ? oacc1[4 * j + 0] : oacc0[4 * j + 0],
                                db ? oacc1[4 * j + 1] : oacc0[4 * j + 1]);
            pk[1] = cvt_pk_bf16(db ? oacc1[4 * j + 2] : oacc0[4 * j + 2],
                                db ? oacc1[4 * j + 3] : oacc0[4 * j + 3]);
            const int d0 = 32 * db + 8 * j + 4 * hi;
            *reinterpret_cast<u32x2*>(op + d0) = pk;
        }
    }
    if (hi == 0) lws[((size_t)half * M_TOT + qrow) * HNUM + h] = l_tot;
}

// ---------------- combine partials: ab = (PO0 + PO1) / (l0 + l1) ----------------
__global__ __launch_bounds__(256) void combine_kernel(const u16* __restrict__ PO,
                                                      const float* __restrict__ lws,
                                                      u16* __restrict__ ab) {
    const int i = (blockIdx.x * 256 + threadIdx.x) * 8;
    const int row = i >> 10;
    const int h = (i & 1023) >> 6;
    const float l0 = lws[(size_t)row * HNUM + h];
    const float l1 = lws[((size_t)M_TOT + row) * HNUM + h];
    const float rl = 1.0f / (l0 + l1);
    const bf16x8 a = *reinterpret_cast<const bf16x8*>(PO + i);
    const bf16x8 c = *reinterpret_cast<const bf16x8*>(PO + (size_t)M_TOT * E_DIM + i);
    u16x8 o;
    #pragma unroll
    for (int j = 0; j < 8; j++)
        o[j] = f2bf(((float)a[j] + (float)c[j]) * rl);
    *reinterpret_cast<u16x8*>(ab + i) = o;
}

extern "C" void kernel_launch(void* const* d_in, const int* in_sizes, int n_in,
                              void* d_out, int out_size, void* d_ws, size_t ws_size,
                              hipStream_t stream) {
    const float* x  = (const float*)d_in[0];
    const int* mask = (const int*)d_in[1];
    const float* Wq = (const float*)d_in[2];
    const float* bq = (const float*)d_in[3];
    const float* Wk = (const float*)d_in[4];
    const float* bk = (const float*)d_in[5];
    const float* Wv = (const float*)d_in[6];
    const float* bv = (const float*)d_in[7];
    const float* Wo = (const float*)d_in[8];
    const float* bo = (const float*)d_in[9];
    float* out = (float*)d_out;

    u16* ws  = (u16*)d_ws;
    const size_t ME = (size_t)M_TOT * E_DIM;         // 4194304
    u16* xb  = ws;                                   // [M][E] bf16 x ; later reused as ab
    u16* wt  = ws + ME;                              // 4x [E][E] bf16 W^T (q,k,v,o)
    u16* qb  = ws + 2 * ME;                          // Q,K,V contiguous [3][M][E]
    u16* kbf = ws + 3 * ME;
    u16* vbf = ws + 4 * ME;
    u64* mbf = (u64*)(ws + 5 * ME);                  // 64 u64 mask bitmaps (512B)
    float* lws = (float*)(ws + 5 * ME + 8192);       // [2][M][H] f32 l-partials (512KB)
    u16* ab  = xb;                                   // attn concat aliases xb
    u16* po  = (u16*)d_out;                          // partial O scratch: 2x[M][E] bf16 = 16MB

    prep_kernel<<<dim3(M_TOT * E_DIM / 1024 + 4096), dim3(256), 0, stream>>>(
        x, xb, mask, mbf, Wq, Wk, Wv, Wo, wt);
    gemm_kernel<u16><<<dim3(E_DIM / 128, M_TOT / 128, 3), dim3(256), 0, stream>>>(
        xb, wt, qb, bq, bk, bv, 0.125f * LOG2E, M_TOT);
    attn_kernel<<<dim3(512), dim3(512), 0, stream>>>(qb, kbf, vbf, mbf, po, lws);
    combine_kernel<<<dim3(M_TOT * E_DIM / 2048), dim3(256), 0, stream>>>(po, lws, ab);
    gemm_kernel<float><<<dim3(E_DIM / 128, M_TOT / 128, 1), dim3(256), 0, stream>>>(
        ab, wt + (size_t)3 * E_DIM * E_DIM, out, bo, bo, bo, 1.0f, M_TOT);
}